// Round 2
// baseline (391.378 us; speedup 1.0000x reference)
//
#include <hip/hip_runtime.h>

#define C_IN 128
#define H_DIM 512
#define O_DIM 128
#define CAP   128   // per-node neighbor capacity; deg ~ Bin(640k,1e-4) = 64±8 (8σ)
#define PAD   16    // counter padding: 1 int per 64B cache line
#define BM    32    // fused-MLP rows per job
#define NBLK  768   // 3 blocks/CU x 256 CU; co-residency guaranteed by __launch_bounds__(256,3)
                    // (LDS 37.5 KB/block -> 4 blocks/CU cap, VGPR bound -> 3)

typedef __attribute__((ext_vector_type(8))) short short8;
typedef __attribute__((ext_vector_type(4))) float f32x4;

__device__ inline unsigned short f2bf(float f) {
    unsigned int u = __float_as_uint(f);
    unsigned int r = (u + 0x7FFF + ((u >> 16) & 1)) >> 16;   // RNE
    return (unsigned short)r;
}
__device__ inline float bf2f(unsigned short s) {
    return __uint_as_float(((unsigned int)s) << 16);
}

// ---------------------------------------------------------------------------
// software grid barrier (single-use counter, zeroed by host memset each call)
// agent-scope release/acquire fences handle cross-XCD L2 visibility.
// ---------------------------------------------------------------------------
__device__ inline void gbar(int* bar, int nblk) {
    __syncthreads();
    __builtin_amdgcn_fence(__ATOMIC_RELEASE, "agent");
    if (threadIdx.x == 0) {
        __hip_atomic_fetch_add(bar, 1, __ATOMIC_RELAXED, __HIP_MEMORY_SCOPE_AGENT);
        int guard = 0;
        while (__hip_atomic_load(bar, __ATOMIC_RELAXED, __HIP_MEMORY_SCOPE_AGENT) < nblk) {
            __builtin_amdgcn_s_sleep(8);
            if (++guard > (1 << 22)) break;   // bounded spin: fail visibly, don't hang
        }
    }
    __syncthreads();
    __builtin_amdgcn_fence(__ATOMIC_ACQUIRE, "agent");
}

// ---------------------------------------------------------------------------
// 32x32 transpose tile + fp32->bf16: dst[c][r] = bf16(src[r][c])
// ---------------------------------------------------------------------------
__device__ inline void tr_tile(float (*tile)[33], const float* __restrict__ src,
                               unsigned short* __restrict__ dst,
                               int R, int Ccols, int bx, int by) {
    const int c0 = bx * 32, r0 = by * 32;
    const int tx = threadIdx.x & 31, ty = threadIdx.x >> 5;   // 32 x 8
#pragma unroll
    for (int i = 0; i < 32; i += 8)
        tile[ty + i][tx] = src[(long)(r0 + ty + i) * Ccols + c0 + tx];
    __syncthreads();
#pragma unroll
    for (int i = 0; i < 32; i += 8)
        dst[(long)(c0 + ty + i) * R + r0 + tx] = f2bf(tile[tx][ty + i]);
    __syncthreads();
}

// ---------------------------------------------------------------------------
// ONE persistent kernel, 3 phases separated by 2 grid barriers:
//  P0: weight transposes (192 tile jobs) + {x->bf16 | edge bucket fill}
//  P1: gather (wave per node, bucket row in registers, shfl-distributed ids)
//  P2: fused MLP (BM=32 rows/job, MFMA, one __syncthreads per job)
// ---------------------------------------------------------------------------
__global__ __launch_bounds__(256, 3)
void fused_all(const float* __restrict__ x, const int* __restrict__ ei,
               const float* __restrict__ w1, const float* __restrict__ bias1,
               const float* __restrict__ w2, const float* __restrict__ bias2,
               unsigned short* __restrict__ h0, unsigned short* __restrict__ w1t,
               unsigned short* __restrict__ w2t, int* __restrict__ cnt_p,
               unsigned short* __restrict__ bucket, int* __restrict__ bar,
               float* __restrict__ out, int N, int E) {
    __shared__ float tile[32][33];
    __shared__ __align__(16) unsigned short h1s[BM][520];

    const int bid = blockIdx.x;
    const int nblk = gridDim.x;
    const int t = threadIdx.x;
    const int lane = t & 63;
    const int wv = t >> 6;          // wave in block 0..3
    const int l16 = lane & 15;
    const int q = lane >> 4;        // quarter id 0..3
    const int q8 = q * 8;

    // ---------------- P0a: weight transposes (uniform per block) ----------
    for (int job = bid; job < 192; job += nblk) {
        if (job < 128) {
            tr_tile(tile, w1, w1t, 2 * C_IN, H_DIM, job & 15, job >> 4);
        } else {
            int j = job - 128;
            tr_tile(tile, w2, w2t, H_DIM, O_DIM, j & 3, j >> 2);
        }
    }

    // ---------------- P0b: x->bf16 convert + edge bucket fill -------------
    {
        const int XJ = N * C_IN / 4;          // float4 convert jobs
        const int FJ = (E + 3) / 4;           // 4-edge fill jobs
        const int gtid = bid * 256 + t;
        const int nthr = nblk * 256;
        const bool al = ((E & 3) == 0);
        for (int j = gtid; j < XJ + FJ; j += nthr) {
            if (j < XJ) {
                int n = j >> 5, c4 = j & 31;
                float4 v = ((const float4*)x)[j];
                ushort4 s;
                s.x = f2bf(v.x); s.y = f2bf(v.y); s.z = f2bf(v.z); s.w = f2bf(v.w);
                *(ushort4*)(h0 + (long)n * (2 * C_IN) + c4 * 4) = s;
            } else {
                int e = (j - XJ) * 4;
                if (al) {
                    int4 r = *(const int4*)(ei + e);
                    int4 c = *(const int4*)(ei + E + e);
                    int s0 = atomicAdd(&cnt_p[r.x * PAD], 1);
                    int s1 = atomicAdd(&cnt_p[r.y * PAD], 1);
                    int s2 = atomicAdd(&cnt_p[r.z * PAD], 1);
                    int s3 = atomicAdd(&cnt_p[r.w * PAD], 1);
                    if (s0 < CAP) bucket[(long)r.x * CAP + s0] = (unsigned short)c.x;
                    if (s1 < CAP) bucket[(long)r.y * CAP + s1] = (unsigned short)c.y;
                    if (s2 < CAP) bucket[(long)r.z * CAP + s2] = (unsigned short)c.z;
                    if (s3 < CAP) bucket[(long)r.w * CAP + s3] = (unsigned short)c.w;
                } else {
                    for (int k = e; k < E && k < e + 4; k++) {
                        int row = ei[k];
                        int col = ei[E + k];
                        int slot = atomicAdd(&cnt_p[row * PAD], 1);
                        if (slot < CAP) bucket[(long)row * CAP + slot] = (unsigned short)col;
                    }
                }
            }
        }
    }

    gbar(&bar[0], nblk);

    // ---------------- P1: gather (wave per node) --------------------------
    for (int n = bid * 4 + wv; n < N; n += nblk * 4) {
        const int g = q;
        const int degt = cnt_p[n * PAD];
        const int deg = min(degt, CAP);

        // full bucket row in registers: lane holds slots {2*lane, 2*lane+1}
        const unsigned int bb = ((const unsigned int*)bucket)[(long)n * (CAP / 2) + lane];

        float acc[8] = {};
        int e = 0;
        for (; e + 16 <= deg; e += 16) {
            int k0 = e + g, k1 = e + 4 + g, k2 = e + 8 + g, k3 = e + 12 + g;
            int c0 = (__shfl(bb, k0 >> 1) >> ((k0 & 1) << 4)) & 0xffff;
            int c1 = (__shfl(bb, k1 >> 1) >> ((k1 & 1) << 4)) & 0xffff;
            int c2 = (__shfl(bb, k2 >> 1) >> ((k2 & 1) << 4)) & 0xffff;
            int c3 = (__shfl(bb, k3 >> 1) >> ((k3 & 1) << 4)) & 0xffff;
            short8 u0 = *(const short8*)(h0 + (long)c0 * (2 * C_IN) + l16 * 8);
            short8 u1 = *(const short8*)(h0 + (long)c1 * (2 * C_IN) + l16 * 8);
            short8 u2 = *(const short8*)(h0 + (long)c2 * (2 * C_IN) + l16 * 8);
            short8 u3 = *(const short8*)(h0 + (long)c3 * (2 * C_IN) + l16 * 8);
#pragma unroll
            for (int j = 0; j < 8; j++)
                acc[j] += (bf2f((unsigned short)u0[j]) + bf2f((unsigned short)u1[j]))
                        + (bf2f((unsigned short)u2[j]) + bf2f((unsigned short)u3[j]));
        }
        if (e + 8 <= deg) {
            int k0 = e + g, k1 = e + 4 + g;
            int c0 = (__shfl(bb, k0 >> 1) >> ((k0 & 1) << 4)) & 0xffff;
            int c1 = (__shfl(bb, k1 >> 1) >> ((k1 & 1) << 4)) & 0xffff;
            short8 u0 = *(const short8*)(h0 + (long)c0 * (2 * C_IN) + l16 * 8);
            short8 u1 = *(const short8*)(h0 + (long)c1 * (2 * C_IN) + l16 * 8);
#pragma unroll
            for (int j = 0; j < 8; j++)
                acc[j] += bf2f((unsigned short)u0[j]) + bf2f((unsigned short)u1[j]);
            e += 8;
        }
        if (e + 4 <= deg) {
            int k = e + g;
            int c = (__shfl(bb, k >> 1) >> ((k & 1) << 4)) & 0xffff;
            short8 u = *(const short8*)(h0 + (long)c * (2 * C_IN) + l16 * 8);
#pragma unroll
            for (int j = 0; j < 8; j++) acc[j] += bf2f((unsigned short)u[j]);
            e += 4;
        }
        {
            int rem = deg - e;            // 0..3
            int k = e + g;
            unsigned int bv = __shfl(bb, k >> 1);   // shfl before divergence
            if (g < rem) {
                int c = (bv >> ((k & 1) << 4)) & 0xffff;
                short8 u = *(const short8*)(h0 + (long)c * (2 * C_IN) + l16 * 8);
#pragma unroll
                for (int j = 0; j < 8; j++) acc[j] += bf2f((unsigned short)u[j]);
            }
        }
#pragma unroll
        for (int j = 0; j < 8; j++) {
            acc[j] += __shfl_xor(acc[j], 16, 64);
            acc[j] += __shfl_xor(acc[j], 32, 64);
        }
        if (lane < 16) {
            float inv = 1.0f / fmaxf((float)degt, 1.0f);
            short8 mv;
#pragma unroll
            for (int j = 0; j < 8; j++) mv[j] = (short)f2bf(acc[j] * inv);
            *(short8*)(h0 + (long)n * (2 * C_IN) + C_IN + l16 * 8) = mv;
        }
    }

    gbar(&bar[16], nblk);

    // ---------------- P2: fused MLP (BM=32 rows per job) ------------------
    const int MJOBS = (N + BM - 1) / BM;
    for (int job = bid; job < MJOBS; job += nblk) {
        const int m0 = job * BM;

        // A-fragments: 2 m-frags x K=256 (identical across the 4 waves)
        short8 a_reg[2][8];
#pragma unroll
        for (int mf = 0; mf < 2; mf++) {
            int gm = m0 + mf * 16 + l16;
            if (gm < N) {
                const unsigned short* ap = h0 + (long)gm * (2 * C_IN) + q8;
#pragma unroll
                for (int s = 0; s < 8; s++) a_reg[mf][s] = *(const short8*)(ap + s * 32);
            } else {
#pragma unroll
                for (int s = 0; s < 8; s++) a_reg[mf][s] = short8{};
            }
        }

        // phase 1 (barrier-free): wave wv -> h1 cols [wv*128, +128), 4 chunks
#pragma unroll
        for (int nc = 0; nc < 4; nc++) {
            const int colbase = wv * 128 + nc * 32;
            f32x4 acc[2][2] = {};
#pragma unroll
            for (int s = 0; s < 8; s++) {
                short8 b0 = *(const short8*)(w1t + (long)(colbase + l16) * 256 + s * 32 + q8);
                short8 b1 = *(const short8*)(w1t + (long)(colbase + 16 + l16) * 256 + s * 32 + q8);
                acc[0][0] = __builtin_amdgcn_mfma_f32_16x16x32_bf16(a_reg[0][s], b0, acc[0][0], 0, 0, 0);
                acc[0][1] = __builtin_amdgcn_mfma_f32_16x16x32_bf16(a_reg[0][s], b1, acc[0][1], 0, 0, 0);
                acc[1][0] = __builtin_amdgcn_mfma_f32_16x16x32_bf16(a_reg[1][s], b0, acc[1][0], 0, 0, 0);
                acc[1][1] = __builtin_amdgcn_mfma_f32_16x16x32_bf16(a_reg[1][s], b1, acc[1][1], 0, 0, 0);
            }
            float bb0 = bias1[colbase + l16];
            float bb1 = bias1[colbase + 16 + l16];
#pragma unroll
            for (int mf = 0; mf < 2; mf++) {
#pragma unroll
                for (int r = 0; r < 4; r++) {
                    int m = mf * 16 + q * 4 + r;
                    h1s[m][colbase + l16]      = f2bf(fmaxf(acc[mf][0][r] + bb0, 0.f));
                    h1s[m][colbase + 16 + l16] = f2bf(fmaxf(acc[mf][1][r] + bb1, 0.f));
                }
            }
        }
        __syncthreads();

        // phase 2: wave wv -> out cols [wv*32, +32), 32 rows, K=512
        f32x4 acc2[2][2] = {};
        const int wn = wv * 32;
#pragma unroll
        for (int ks = 0; ks < 16; ks++) {
            short8 a0 = *(const short8*)&h1s[l16][ks * 32 + q8];
            short8 a1 = *(const short8*)&h1s[16 + l16][ks * 32 + q8];
            short8 b0 = *(const short8*)(w2t + (long)(wn + l16) * H_DIM + ks * 32 + q8);
            short8 b1 = *(const short8*)(w2t + (long)(wn + 16 + l16) * H_DIM + ks * 32 + q8);
            acc2[0][0] = __builtin_amdgcn_mfma_f32_16x16x32_bf16(a0, b0, acc2[0][0], 0, 0, 0);
            acc2[0][1] = __builtin_amdgcn_mfma_f32_16x16x32_bf16(a0, b1, acc2[0][1], 0, 0, 0);
            acc2[1][0] = __builtin_amdgcn_mfma_f32_16x16x32_bf16(a1, b0, acc2[1][0], 0, 0, 0);
            acc2[1][1] = __builtin_amdgcn_mfma_f32_16x16x32_bf16(a1, b1, acc2[1][1], 0, 0, 0);
        }
#pragma unroll
        for (int mf = 0; mf < 2; mf++) {
#pragma unroll
            for (int nf = 0; nf < 2; nf++) {
                int gn = wn + nf * 16 + l16;
                float bb = bias2[gn];
#pragma unroll
                for (int r = 0; r < 4; r++) {
                    int gm = m0 + mf * 16 + q * 4 + r;
                    if (gm < N) out[(long)gm * O_DIM + gn] = acc2[mf][nf][r] + bb;
                }
            }
        }
        __syncthreads();   // h1s reuse guard for blocks taking a 2nd job
    }
}

extern "C" void kernel_launch(void* const* d_in, const int* in_sizes, int n_in,
                              void* d_out, int out_size, void* d_ws, size_t ws_size,
                              hipStream_t stream) {
    const float* x  = (const float*)d_in[0];   // [N, C]
    const int*   ei = (const int*)d_in[1];     // [2, E]
    const float* w1 = (const float*)d_in[2];   // [2C, H]
    const float* b1 = (const float*)d_in[3];   // [H]
    const float* w2 = (const float*)d_in[4];   // [H, O]
    const float* b2 = (const float*)d_in[5];   // [O]
    float* out = (float*)d_out;                // [N, O]

    const int N = in_sizes[0] / C_IN;
    const int E = in_sizes[1] / 2;

    // ws layout: h0b [N][256] bf16 | w1t [512][256] bf16 | w2t [128][512] bf16
    //            | cnt_p [N*PAD] int | bar [64] int | bucket [N*CAP] ushort
    unsigned short* h0b = (unsigned short*)d_ws;
    unsigned short* w1t = h0b + (size_t)N * (2 * C_IN);
    unsigned short* w2t = w1t + (size_t)H_DIM * (2 * C_IN);
    int* cnt_p = (int*)(w2t + (size_t)O_DIM * H_DIM);
    int* bar   = cnt_p + (size_t)N * PAD;
    unsigned short* bucket = (unsigned short*)(bar + 64);

    // zero counters + barrier words (ws is poisoned between iterations)
    hipMemsetAsync(cnt_p, 0, ((size_t)N * PAD + 64) * sizeof(int), stream);
    fused_all<<<NBLK, 256, 0, stream>>>(x, ei, w1, b1, w2, b2,
                                        h0b, w1t, w2t, cnt_p, bucket, bar, out, N, E);
}

// Round 3
// 244.749 us; speedup vs baseline: 1.5991x; 1.5991x over previous
//
#include <hip/hip_runtime.h>

#define C_IN 128
#define H_DIM 512
#define O_DIM 128
#define CAP   128   // per-node neighbor capacity; deg ~ Bin(640k,1e-4) = 64±8 (8σ)
#define PAD   16    // counter padding: 1 int per 64B cache line
#define BM    32    // fused-MLP rows per job

typedef __attribute__((ext_vector_type(8))) short short8;
typedef __attribute__((ext_vector_type(4))) float f32x4;

__device__ inline unsigned short f2bf(float f) {
    unsigned int u = __float_as_uint(f);
    unsigned int r = (u + 0x7FFF + ((u >> 16) & 1)) >> 16;   // RNE
    return (unsigned short)r;
}
__device__ inline float bf2f(unsigned short s) {
    return __uint_as_float(((unsigned int)s) << 16);
}

// ---------------------------------------------------------------------------
// software grid barrier (single-use counter, zeroed by host memset each call)
// agent-scope release/acquire fences handle cross-XCD L2 visibility.
// Grid size is chosen via the occupancy API so all blocks are co-resident.
// ---------------------------------------------------------------------------
__device__ inline void gbar(int* bar, int nblk) {
    __syncthreads();
    __builtin_amdgcn_fence(__ATOMIC_RELEASE, "agent");
    if (threadIdx.x == 0) {
        __hip_atomic_fetch_add(bar, 1, __ATOMIC_RELAXED, __HIP_MEMORY_SCOPE_AGENT);
        int guard = 0;
        while (__hip_atomic_load(bar, __ATOMIC_RELAXED, __HIP_MEMORY_SCOPE_AGENT) < nblk) {
            __builtin_amdgcn_s_sleep(8);
            if (++guard > (1 << 22)) break;   // bounded spin: fail visibly, don't hang
        }
    }
    __syncthreads();
    __builtin_amdgcn_fence(__ATOMIC_ACQUIRE, "agent");
}

// LDS overlay: tile used only in P0, h1s only in P2 (grid barriers between)
union SMem {
    float tile[32][33];                                // 4224 B
    unsigned short h1s[BM][520];                       // 33280 B
};

// ---------------------------------------------------------------------------
// 32x32 transpose tile + fp32->bf16: dst[c][r] = bf16(src[r][c])
// ---------------------------------------------------------------------------
__device__ inline void tr_tile(float (*tile)[33], const float* __restrict__ src,
                               unsigned short* __restrict__ dst,
                               int R, int Ccols, int bx, int by) {
    const int c0 = bx * 32, r0 = by * 32;
    const int tx = threadIdx.x & 31, ty = threadIdx.x >> 5;   // 32 x 8
#pragma unroll
    for (int i = 0; i < 32; i += 8)
        tile[ty + i][tx] = src[(long)(r0 + ty + i) * Ccols + c0 + tx];
    __syncthreads();
#pragma unroll
    for (int i = 0; i < 32; i += 8)
        dst[(long)(c0 + ty + i) * R + r0 + tx] = f2bf(tile[tx][ty + i]);
    __syncthreads();
}

// ---------------------------------------------------------------------------
// ONE persistent kernel, 3 phases separated by 2 grid barriers:
//  P0: weight transposes (192 tile jobs) + {x->bf16 | edge bucket fill}
//  P1: gather (wave per node, bucket row in registers, shfl-distributed ids)
//  P2: fused MLP (BM=32 rows/job, MFMA, one __syncthreads per job)
// NOTE: plain __launch_bounds__(256) — the (256,3) variant made the
// allocator pin VGPR=64 and spill a_reg to scratch (+35MB writes, R2).
// ---------------------------------------------------------------------------
__global__ __launch_bounds__(256)
void fused_all(const float* __restrict__ x, const int* __restrict__ ei,
               const float* __restrict__ w1, const float* __restrict__ bias1,
               const float* __restrict__ w2, const float* __restrict__ bias2,
               unsigned short* __restrict__ h0, unsigned short* __restrict__ w1t,
               unsigned short* __restrict__ w2t, int* __restrict__ cnt_p,
               unsigned short* __restrict__ bucket, int* __restrict__ bar,
               float* __restrict__ out, int N, int E) {
    __shared__ SMem sm;

    const int bid = blockIdx.x;
    const int nblk = gridDim.x;
    const int t = threadIdx.x;
    const int lane = t & 63;
    const int wv = t >> 6;          // wave in block 0..3
    const int l16 = lane & 15;
    const int q = lane >> 4;        // quarter id 0..3
    const int q8 = q * 8;

    // ---------------- P0a: weight transposes (uniform per block) ----------
    for (int job = bid; job < 192; job += nblk) {
        if (job < 128) {
            tr_tile(sm.tile, w1, w1t, 2 * C_IN, H_DIM, job & 15, job >> 4);
        } else {
            int j = job - 128;
            tr_tile(sm.tile, w2, w2t, H_DIM, O_DIM, j & 3, j >> 2);
        }
    }

    // ---------------- P0b: x->bf16 convert + edge bucket fill -------------
    {
        const int XJ = N * C_IN / 4;          // float4 convert jobs
        const int FJ = (E + 3) / 4;           // 4-edge fill jobs
        const int gtid = bid * 256 + t;
        const int nthr = nblk * 256;
        const bool al = ((E & 3) == 0);
        for (int j = gtid; j < XJ + FJ; j += nthr) {
            if (j < XJ) {
                int n = j >> 5, c4 = j & 31;
                float4 v = ((const float4*)x)[j];
                ushort4 s;
                s.x = f2bf(v.x); s.y = f2bf(v.y); s.z = f2bf(v.z); s.w = f2bf(v.w);
                *(ushort4*)(h0 + (long)n * (2 * C_IN) + c4 * 4) = s;
            } else {
                int e = (j - XJ) * 4;
                if (al) {
                    int4 r = *(const int4*)(ei + e);
                    int4 c = *(const int4*)(ei + E + e);
                    int s0 = atomicAdd(&cnt_p[r.x * PAD], 1);
                    int s1 = atomicAdd(&cnt_p[r.y * PAD], 1);
                    int s2 = atomicAdd(&cnt_p[r.z * PAD], 1);
                    int s3 = atomicAdd(&cnt_p[r.w * PAD], 1);
                    if (s0 < CAP) bucket[(long)r.x * CAP + s0] = (unsigned short)c.x;
                    if (s1 < CAP) bucket[(long)r.y * CAP + s1] = (unsigned short)c.y;
                    if (s2 < CAP) bucket[(long)r.z * CAP + s2] = (unsigned short)c.z;
                    if (s3 < CAP) bucket[(long)r.w * CAP + s3] = (unsigned short)c.w;
                } else {
                    for (int k = e; k < E && k < e + 4; k++) {
                        int row = ei[k];
                        int col = ei[E + k];
                        int slot = atomicAdd(&cnt_p[row * PAD], 1);
                        if (slot < CAP) bucket[(long)row * CAP + slot] = (unsigned short)col;
                    }
                }
            }
        }
    }

    gbar(&bar[0], nblk);

    // ---------------- P1: gather (wave per node) --------------------------
    for (int n = bid * 4 + wv; n < N; n += nblk * 4) {
        const int g = q;
        const int degt = cnt_p[n * PAD];
        const int deg = min(degt, CAP);

        // full bucket row in registers: lane holds slots {2*lane, 2*lane+1}
        const unsigned int bb = ((const unsigned int*)bucket)[(long)n * (CAP / 2) + lane];

        float acc[8] = {};
        int e = 0;
        for (; e + 16 <= deg; e += 16) {
            int k0 = e + g, k1 = e + 4 + g, k2 = e + 8 + g, k3 = e + 12 + g;
            int c0 = (__shfl(bb, k0 >> 1) >> ((k0 & 1) << 4)) & 0xffff;
            int c1 = (__shfl(bb, k1 >> 1) >> ((k1 & 1) << 4)) & 0xffff;
            int c2 = (__shfl(bb, k2 >> 1) >> ((k2 & 1) << 4)) & 0xffff;
            int c3 = (__shfl(bb, k3 >> 1) >> ((k3 & 1) << 4)) & 0xffff;
            short8 u0 = *(const short8*)(h0 + (long)c0 * (2 * C_IN) + l16 * 8);
            short8 u1 = *(const short8*)(h0 + (long)c1 * (2 * C_IN) + l16 * 8);
            short8 u2 = *(const short8*)(h0 + (long)c2 * (2 * C_IN) + l16 * 8);
            short8 u3 = *(const short8*)(h0 + (long)c3 * (2 * C_IN) + l16 * 8);
#pragma unroll
            for (int j = 0; j < 8; j++)
                acc[j] += (bf2f((unsigned short)u0[j]) + bf2f((unsigned short)u1[j]))
                        + (bf2f((unsigned short)u2[j]) + bf2f((unsigned short)u3[j]));
        }
        if (e + 8 <= deg) {
            int k0 = e + g, k1 = e + 4 + g;
            int c0 = (__shfl(bb, k0 >> 1) >> ((k0 & 1) << 4)) & 0xffff;
            int c1 = (__shfl(bb, k1 >> 1) >> ((k1 & 1) << 4)) & 0xffff;
            short8 u0 = *(const short8*)(h0 + (long)c0 * (2 * C_IN) + l16 * 8);
            short8 u1 = *(const short8*)(h0 + (long)c1 * (2 * C_IN) + l16 * 8);
#pragma unroll
            for (int j = 0; j < 8; j++)
                acc[j] += bf2f((unsigned short)u0[j]) + bf2f((unsigned short)u1[j]);
            e += 8;
        }
        if (e + 4 <= deg) {
            int k = e + g;
            int c = (__shfl(bb, k >> 1) >> ((k & 1) << 4)) & 0xffff;
            short8 u = *(const short8*)(h0 + (long)c * (2 * C_IN) + l16 * 8);
#pragma unroll
            for (int j = 0; j < 8; j++) acc[j] += bf2f((unsigned short)u[j]);
            e += 4;
        }
        {
            int rem = deg - e;            // 0..3
            int k = e + g;
            unsigned int bv = __shfl(bb, k >> 1);   // shfl before divergence
            if (g < rem) {
                int c = (bv >> ((k & 1) << 4)) & 0xffff;
                short8 u = *(const short8*)(h0 + (long)c * (2 * C_IN) + l16 * 8);
#pragma unroll
                for (int j = 0; j < 8; j++) acc[j] += bf2f((unsigned short)u[j]);
            }
        }
#pragma unroll
        for (int j = 0; j < 8; j++) {
            acc[j] += __shfl_xor(acc[j], 16, 64);
            acc[j] += __shfl_xor(acc[j], 32, 64);
        }
        if (lane < 16) {
            float inv = 1.0f / fmaxf((float)degt, 1.0f);
            short8 mv;
#pragma unroll
            for (int j = 0; j < 8; j++) mv[j] = (short)f2bf(acc[j] * inv);
            *(short8*)(h0 + (long)n * (2 * C_IN) + C_IN + l16 * 8) = mv;
        }
    }

    gbar(&bar[16], nblk);

    // ---------------- P2: fused MLP (BM=32 rows per job) ------------------
    const int MJOBS = (N + BM - 1) / BM;
    for (int job = bid; job < MJOBS; job += nblk) {
        const int m0 = job * BM;

        // A-fragments: 2 m-frags x K=256 (identical across the 4 waves)
        short8 a_reg[2][8];
#pragma unroll
        for (int mf = 0; mf < 2; mf++) {
            int gm = m0 + mf * 16 + l16;
            if (gm < N) {
                const unsigned short* ap = h0 + (long)gm * (2 * C_IN) + q8;
#pragma unroll
                for (int s = 0; s < 8; s++) a_reg[mf][s] = *(const short8*)(ap + s * 32);
            } else {
#pragma unroll
                for (int s = 0; s < 8; s++) a_reg[mf][s] = short8{};
            }
        }

        // phase 1 (barrier-free): wave wv -> h1 cols [wv*128, +128), 4 chunks
#pragma unroll
        for (int nc = 0; nc < 4; nc++) {
            const int colbase = wv * 128 + nc * 32;
            f32x4 acc[2][2] = {};
#pragma unroll
            for (int s = 0; s < 8; s++) {
                short8 b0 = *(const short8*)(w1t + (long)(colbase + l16) * 256 + s * 32 + q8);
                short8 b1 = *(const short8*)(w1t + (long)(colbase + 16 + l16) * 256 + s * 32 + q8);
                acc[0][0] = __builtin_amdgcn_mfma_f32_16x16x32_bf16(a_reg[0][s], b0, acc[0][0], 0, 0, 0);
                acc[0][1] = __builtin_amdgcn_mfma_f32_16x16x32_bf16(a_reg[0][s], b1, acc[0][1], 0, 0, 0);
                acc[1][0] = __builtin_amdgcn_mfma_f32_16x16x32_bf16(a_reg[1][s], b0, acc[1][0], 0, 0, 0);
                acc[1][1] = __builtin_amdgcn_mfma_f32_16x16x32_bf16(a_reg[1][s], b1, acc[1][1], 0, 0, 0);
            }
            float bb0 = bias1[colbase + l16];
            float bb1 = bias1[colbase + 16 + l16];
#pragma unroll
            for (int mf = 0; mf < 2; mf++) {
#pragma unroll
                for (int r = 0; r < 4; r++) {
                    int m = mf * 16 + q * 4 + r;
                    sm.h1s[m][colbase + l16]      = f2bf(fmaxf(acc[mf][0][r] + bb0, 0.f));
                    sm.h1s[m][colbase + 16 + l16] = f2bf(fmaxf(acc[mf][1][r] + bb1, 0.f));
                }
            }
        }
        __syncthreads();

        // phase 2: wave wv -> out cols [wv*32, +32), 32 rows, K=512
        f32x4 acc2[2][2] = {};
        const int wn = wv * 32;
#pragma unroll
        for (int ks = 0; ks < 16; ks++) {
            short8 a0 = *(const short8*)&sm.h1s[l16][ks * 32 + q8];
            short8 a1 = *(const short8*)&sm.h1s[16 + l16][ks * 32 + q8];
            short8 b0 = *(const short8*)(w2t + (long)(wn + l16) * H_DIM + ks * 32 + q8);
            short8 b1 = *(const short8*)(w2t + (long)(wn + 16 + l16) * H_DIM + ks * 32 + q8);
            acc2[0][0] = __builtin_amdgcn_mfma_f32_16x16x32_bf16(a0, b0, acc2[0][0], 0, 0, 0);
            acc2[0][1] = __builtin_amdgcn_mfma_f32_16x16x32_bf16(a0, b1, acc2[0][1], 0, 0, 0);
            acc2[1][0] = __builtin_amdgcn_mfma_f32_16x16x32_bf16(a1, b0, acc2[1][0], 0, 0, 0);
            acc2[1][1] = __builtin_amdgcn_mfma_f32_16x16x32_bf16(a1, b1, acc2[1][1], 0, 0, 0);
        }
#pragma unroll
        for (int mf = 0; mf < 2; mf++) {
#pragma unroll
            for (int nf = 0; nf < 2; nf++) {
                int gn = wn + nf * 16 + l16;
                float bb = bias2[gn];
#pragma unroll
                for (int r = 0; r < 4; r++) {
                    int gm = m0 + mf * 16 + q * 4 + r;
                    if (gm < N) out[(long)gm * O_DIM + gn] = acc2[mf][nf][r] + bb;
                }
            }
        }
        __syncthreads();   // h1s reuse guard for blocks taking a 2nd job
    }
}

extern "C" void kernel_launch(void* const* d_in, const int* in_sizes, int n_in,
                              void* d_out, int out_size, void* d_ws, size_t ws_size,
                              hipStream_t stream) {
    const float* x  = (const float*)d_in[0];   // [N, C]
    const int*   ei = (const int*)d_in[1];     // [2, E]
    const float* w1 = (const float*)d_in[2];   // [2C, H]
    const float* b1 = (const float*)d_in[3];   // [H]
    const float* w2 = (const float*)d_in[4];   // [H, O]
    const float* b2 = (const float*)d_in[5];   // [O]
    float* out = (float*)d_out;                // [N, O]

    const int N = in_sizes[0] / C_IN;
    const int E = in_sizes[1] / 2;

    // ws layout: h0b [N][256] bf16 | w1t [512][256] bf16 | w2t [128][512] bf16
    //            | cnt_p [N*PAD] int | bar [64] int | bucket [N*CAP] ushort
    unsigned short* h0b = (unsigned short*)d_ws;
    unsigned short* w1t = h0b + (size_t)N * (2 * C_IN);
    unsigned short* w2t = w1t + (size_t)H_DIM * (2 * C_IN);
    int* cnt_p = (int*)(w2t + (size_t)O_DIM * H_DIM);
    int* bar   = cnt_p + (size_t)N * PAD;
    unsigned short* bucket = (unsigned short*)(bar + 64);

    // grid size = blocks/CU (from occupancy API, so the grid barrier is safe
    // under whatever VGPR/LDS allocation the compiler chose) x 256 CUs
    static int g_nblk = 0;
    if (g_nblk == 0) {
        int occ = 0;
        hipError_t err = hipOccupancyMaxActiveBlocksPerMultiprocessor(&occ, fused_all, 256, 0);
        if (err != hipSuccess || occ < 1) occ = 1;
        if (occ > 4) occ = 4;
        g_nblk = occ * 256;
    }

    // zero counters + barrier words (ws is poisoned between iterations)
    hipMemsetAsync(cnt_p, 0, ((size_t)N * PAD + 64) * sizeof(int), stream);
    fused_all<<<g_nblk, 256, 0, stream>>>(x, ei, w1, b1, w2, b2,
                                          h0b, w1t, w2t, cnt_p, bucket, bar, out, N, E);
}

// Round 4
// 139.139 us; speedup vs baseline: 2.8129x; 1.7590x over previous
//
#include <hip/hip_runtime.h>

#define C_IN 128
#define H_DIM 512
#define O_DIM 128
#define CAP   128   // per-node neighbor capacity; deg ~ Bin(640k,1e-4) = 64±8 (8σ)
#define PAD   16    // counter padding: 1 int per 64B cache line
#define BM    32    // fused-MLP rows per block

typedef __attribute__((ext_vector_type(8))) short short8;
typedef __attribute__((ext_vector_type(4))) float f32x4;

__device__ inline unsigned short f2bf(float f) {
    unsigned int u = __float_as_uint(f);
    unsigned int r = (u + 0x7FFF + ((u >> 16) & 1)) >> 16;   // RNE
    return (unsigned short)r;
}
__device__ inline float bf2f(unsigned short s) {
    return __uint_as_float(((unsigned int)s) << 16);
}

// ---------------------------------------------------------------------------
// 32x32 transpose tile + fp32->bf16: dst[c][r] = bf16(src[r][c])
// ---------------------------------------------------------------------------
__device__ inline void tr_tile(const float* __restrict__ src, unsigned short* __restrict__ dst,
                               int R, int Ccols, int bx, int by) {
    __shared__ float tile[32][33];
    const int c0 = bx * 32, r0 = by * 32;
    const int tx = threadIdx.x & 31, ty = threadIdx.x >> 5;   // 32 x 8
#pragma unroll
    for (int i = 0; i < 32; i += 8)
        tile[ty + i][tx] = src[(long)(r0 + ty + i) * Ccols + c0 + tx];
    __syncthreads();
#pragma unroll
    for (int i = 0; i < 32; i += 8)
        dst[(long)(c0 + ty + i) * R + r0 + tx] = f2bf(tile[tx][ty + i]);
}

// ---------------------------------------------------------------------------
// prep+fill merged (cnt_p pre-zeroed by a 640KB memset):
//  blocks 0..191: one 32x32 weight-transpose tile each
//  all blocks: grid-stride over {x->bf16 convert jobs} ++ {4-edge fill jobs}
// ---------------------------------------------------------------------------
__global__ __launch_bounds__(256)
void prep_fill(const float* __restrict__ w1, unsigned short* __restrict__ w1t,
               const float* __restrict__ w2, unsigned short* __restrict__ w2t,
               const float* __restrict__ x, unsigned short* __restrict__ h0,
               const int* __restrict__ ei, int* __restrict__ cnt_p,
               unsigned short* __restrict__ bucket, int N, int E) {
    const int bid = blockIdx.x;
    if (bid < 192) {
        if (bid < 128) tr_tile(w1, w1t, 2 * C_IN, H_DIM, bid & 15, bid >> 4);
        else { int j = bid - 128; tr_tile(w2, w2t, H_DIM, O_DIM, j & 3, j >> 2); }
    }

    const int XJ = N * C_IN / 4;          // float4 convert jobs
    const int FJ = (E + 3) / 4;           // 4-edge fill jobs
    const int gtid = bid * 256 + threadIdx.x;
    const int nthr = gridDim.x * 256;
    const bool al = ((E & 3) == 0);
    for (int j = gtid; j < XJ + FJ; j += nthr) {
        if (j < XJ) {
            int n = j >> 5, c4 = j & 31;
            float4 v = ((const float4*)x)[j];
            ushort4 s;
            s.x = f2bf(v.x); s.y = f2bf(v.y); s.z = f2bf(v.z); s.w = f2bf(v.w);
            *(ushort4*)(h0 + (long)n * (2 * C_IN) + c4 * 4) = s;
        } else {
            int e = (j - XJ) * 4;
            if (al) {
                int4 r = *(const int4*)(ei + e);
                int4 c = *(const int4*)(ei + E + e);
                int s0 = atomicAdd(&cnt_p[r.x * PAD], 1);
                int s1 = atomicAdd(&cnt_p[r.y * PAD], 1);
                int s2 = atomicAdd(&cnt_p[r.z * PAD], 1);
                int s3 = atomicAdd(&cnt_p[r.w * PAD], 1);
                if (s0 < CAP) bucket[(long)r.x * CAP + s0] = (unsigned short)c.x;
                if (s1 < CAP) bucket[(long)r.y * CAP + s1] = (unsigned short)c.y;
                if (s2 < CAP) bucket[(long)r.z * CAP + s2] = (unsigned short)c.z;
                if (s3 < CAP) bucket[(long)r.w * CAP + s3] = (unsigned short)c.w;
            } else {
                for (int k = e; k < E && k < e + 4; k++) {
                    int row = ei[k];
                    int col = ei[E + k];
                    int slot = atomicAdd(&cnt_p[row * PAD], 1);
                    if (slot < CAP) bucket[(long)row * CAP + slot] = (unsigned short)col;
                }
            }
        }
    }
}

// ---------------------------------------------------------------------------
// gather v3: one wave per dst node, QUARTER-wave (16 lanes x 16B short8) per
// edge row. Whole bucket row (256B) pre-loaded into ONE uint register per
// lane; neighbor ids distributed via __shfl (register-file read, ~30cy)
// instead of per-edge L2 loads. Main stage: 32 edges/iter = 8 short8 loads
// in flight per lane (deg~64 -> exactly ~2 iterations), then 16/8/4/rem.
// ---------------------------------------------------------------------------
__global__ __launch_bounds__(256)
void gather_kernel(const unsigned short* __restrict__ bucket,
                   const int* __restrict__ cnt_p, unsigned short* __restrict__ h0,
                   int N) {
    const int lane = threadIdx.x & 63;
    const int n = blockIdx.x * 4 + (threadIdx.x >> 6);
    if (n >= N) return;
    const int g = lane >> 4;          // quarter id 0..3
    const int l16 = lane & 15;
    const int degt = cnt_p[n * PAD];
    const int deg = min(degt, CAP);

    // full bucket row in registers: lane holds slots {2*lane, 2*lane+1}
    const unsigned int bb = ((const unsigned int*)bucket)[(long)n * (CAP / 2) + lane];

    float acc[8] = {};
    int e = 0;
    for (; e + 32 <= deg; e += 32) {
        int c[8];
#pragma unroll
        for (int i = 0; i < 8; i++) {
            int k = e + 4 * i + g;
            c[i] = (__shfl(bb, k >> 1) >> ((k & 1) << 4)) & 0xffff;
        }
        short8 u[8];
#pragma unroll
        for (int i = 0; i < 8; i++)
            u[i] = *(const short8*)(h0 + (long)c[i] * (2 * C_IN) + l16 * 8);
#pragma unroll
        for (int j = 0; j < 8; j++) {
            float s0 = bf2f((unsigned short)u[0][j]) + bf2f((unsigned short)u[1][j]);
            float s1 = bf2f((unsigned short)u[2][j]) + bf2f((unsigned short)u[3][j]);
            float s2 = bf2f((unsigned short)u[4][j]) + bf2f((unsigned short)u[5][j]);
            float s3 = bf2f((unsigned short)u[6][j]) + bf2f((unsigned short)u[7][j]);
            acc[j] += (s0 + s1) + (s2 + s3);
        }
    }
    if (e + 16 <= deg) {
        int k0 = e + g, k1 = e + 4 + g, k2 = e + 8 + g, k3 = e + 12 + g;
        int c0 = (__shfl(bb, k0 >> 1) >> ((k0 & 1) << 4)) & 0xffff;
        int c1 = (__shfl(bb, k1 >> 1) >> ((k1 & 1) << 4)) & 0xffff;
        int c2 = (__shfl(bb, k2 >> 1) >> ((k2 & 1) << 4)) & 0xffff;
        int c3 = (__shfl(bb, k3 >> 1) >> ((k3 & 1) << 4)) & 0xffff;
        short8 u0 = *(const short8*)(h0 + (long)c0 * (2 * C_IN) + l16 * 8);
        short8 u1 = *(const short8*)(h0 + (long)c1 * (2 * C_IN) + l16 * 8);
        short8 u2 = *(const short8*)(h0 + (long)c2 * (2 * C_IN) + l16 * 8);
        short8 u3 = *(const short8*)(h0 + (long)c3 * (2 * C_IN) + l16 * 8);
#pragma unroll
        for (int j = 0; j < 8; j++)
            acc[j] += (bf2f((unsigned short)u0[j]) + bf2f((unsigned short)u1[j]))
                    + (bf2f((unsigned short)u2[j]) + bf2f((unsigned short)u3[j]));
        e += 16;
    }
    if (e + 8 <= deg) {
        int k0 = e + g, k1 = e + 4 + g;
        int c0 = (__shfl(bb, k0 >> 1) >> ((k0 & 1) << 4)) & 0xffff;
        int c1 = (__shfl(bb, k1 >> 1) >> ((k1 & 1) << 4)) & 0xffff;
        short8 u0 = *(const short8*)(h0 + (long)c0 * (2 * C_IN) + l16 * 8);
        short8 u1 = *(const short8*)(h0 + (long)c1 * (2 * C_IN) + l16 * 8);
#pragma unroll
        for (int j = 0; j < 8; j++)
            acc[j] += bf2f((unsigned short)u0[j]) + bf2f((unsigned short)u1[j]);
        e += 8;
    }
    if (e + 4 <= deg) {
        int k = e + g;
        int c = (__shfl(bb, k >> 1) >> ((k & 1) << 4)) & 0xffff;
        short8 u = *(const short8*)(h0 + (long)c * (2 * C_IN) + l16 * 8);
#pragma unroll
        for (int j = 0; j < 8; j++) acc[j] += bf2f((unsigned short)u[j]);
        e += 4;
    }
    {
        int rem = deg - e;            // 0..3
        int k = e + g;
        unsigned int bv = __shfl(bb, k >> 1);   // shfl before divergence
        if (g < rem) {
            int c = (bv >> ((k & 1) << 4)) & 0xffff;
            short8 u = *(const short8*)(h0 + (long)c * (2 * C_IN) + l16 * 8);
#pragma unroll
            for (int j = 0; j < 8; j++) acc[j] += bf2f((unsigned short)u[j]);
        }
    }
#pragma unroll
    for (int j = 0; j < 8; j++) {
        acc[j] += __shfl_xor(acc[j], 16, 64);
        acc[j] += __shfl_xor(acc[j], 32, 64);
    }
    if (lane < 16) {
        float inv = 1.0f / fmaxf((float)degt, 1.0f);
        short8 mv;
#pragma unroll
        for (int j = 0; j < 8; j++) mv[j] = (short)f2bf(acc[j] * inv);
        *(short8*)(h0 + (long)n * (2 * C_IN) + C_IN + l16 * 8) = mv;
    }
}

// ---------------------------------------------------------------------------
// fused MLP: out[32 rows] = relu(h0_blk @ w1t^T + b1) @ w2t^T + b2
// BM=32, 313 blocks (one job each). Phase 1 BARRIER-FREE: wave w owns h1
// cols [w*128,+128) for BOTH 16-row m-frags; A-frags in registers; B-frags
// direct from L2-hot w1t. h1 (bf16) -> 33.3 KB LDS. ONE barrier total.
// Phase 2: A-frags from LDS h1s, B-frags direct from L2-hot w2t.
// Plain launch_bounds: the (256,3) pin caused VGPR=64 + scratch spill (R2).
// ---------------------------------------------------------------------------
__global__ __launch_bounds__(256)
void fused_mlp(const unsigned short* __restrict__ h0,    // [N][256] bf16
               const unsigned short* __restrict__ w1t,   // [512][256] bf16
               const float* __restrict__ bias1,
               const unsigned short* __restrict__ w2t,   // [128][512] bf16
               const float* __restrict__ bias2,
               float* __restrict__ out, int M) {
    __shared__ __align__(16) unsigned short h1s[BM][520];

    const int t = threadIdx.x;
    const int m0 = blockIdx.x * BM;
    const int lane = t & 63;
    const int w = t >> 6;
    const int l16 = lane & 15;
    const int q = lane >> 4;        // 0..3
    const int q8 = q * 8;

    // A-fragments: 2 m-frags x K=256 (identical across the 4 waves)
    short8 a_reg[2][8];
#pragma unroll
    for (int mf = 0; mf < 2; mf++) {
        int gm = m0 + mf * 16 + l16;
        if (gm < M) {
            const unsigned short* ap = h0 + (long)gm * (2 * C_IN) + q8;
#pragma unroll
            for (int s = 0; s < 8; s++) a_reg[mf][s] = *(const short8*)(ap + s * 32);
        } else {
#pragma unroll
            for (int s = 0; s < 8; s++) a_reg[mf][s] = short8{};
        }
    }

    // phase 1: wave w -> h1 cols [w*128, w*128+128), 4 chunks of 32
#pragma unroll
    for (int nc = 0; nc < 4; nc++) {
        const int colbase = w * 128 + nc * 32;
        f32x4 acc[2][2] = {};
#pragma unroll
        for (int s = 0; s < 8; s++) {
            short8 b0 = *(const short8*)(w1t + (long)(colbase + l16) * 256 + s * 32 + q8);
            short8 b1 = *(const short8*)(w1t + (long)(colbase + 16 + l16) * 256 + s * 32 + q8);
            acc[0][0] = __builtin_amdgcn_mfma_f32_16x16x32_bf16(a_reg[0][s], b0, acc[0][0], 0, 0, 0);
            acc[0][1] = __builtin_amdgcn_mfma_f32_16x16x32_bf16(a_reg[0][s], b1, acc[0][1], 0, 0, 0);
            acc[1][0] = __builtin_amdgcn_mfma_f32_16x16x32_bf16(a_reg[1][s], b0, acc[1][0], 0, 0, 0);
            acc[1][1] = __builtin_amdgcn_mfma_f32_16x16x32_bf16(a_reg[1][s], b1, acc[1][1], 0, 0, 0);
        }
        float bb0 = bias1[colbase + l16];
        float bb1 = bias1[colbase + 16 + l16];
#pragma unroll
        for (int mf = 0; mf < 2; mf++) {
#pragma unroll
            for (int r = 0; r < 4; r++) {
                int m = mf * 16 + q * 4 + r;
                h1s[m][colbase + l16]      = f2bf(fmaxf(acc[mf][0][r] + bb0, 0.f));
                h1s[m][colbase + 16 + l16] = f2bf(fmaxf(acc[mf][1][r] + bb1, 0.f));
            }
        }
    }
    __syncthreads();

    // phase 2: wave w -> out cols [w*32, w*32+32), 32 rows, K=512
    f32x4 acc2[2][2] = {};
    const int wn = w * 32;
#pragma unroll
    for (int ks = 0; ks < 16; ks++) {
        short8 a0 = *(const short8*)&h1s[l16][ks * 32 + q8];
        short8 a1 = *(const short8*)&h1s[16 + l16][ks * 32 + q8];
        short8 b0 = *(const short8*)(w2t + (long)(wn + l16) * H_DIM + ks * 32 + q8);
        short8 b1 = *(const short8*)(w2t + (long)(wn + 16 + l16) * H_DIM + ks * 32 + q8);
        acc2[0][0] = __builtin_amdgcn_mfma_f32_16x16x32_bf16(a0, b0, acc2[0][0], 0, 0, 0);
        acc2[0][1] = __builtin_amdgcn_mfma_f32_16x16x32_bf16(a0, b1, acc2[0][1], 0, 0, 0);
        acc2[1][0] = __builtin_amdgcn_mfma_f32_16x16x32_bf16(a1, b0, acc2[1][0], 0, 0, 0);
        acc2[1][1] = __builtin_amdgcn_mfma_f32_16x16x32_bf16(a1, b1, acc2[1][1], 0, 0, 0);
    }
#pragma unroll
    for (int mf = 0; mf < 2; mf++) {
#pragma unroll
        for (int nf = 0; nf < 2; nf++) {
            int gn = wn + nf * 16 + l16;
            float bb = bias2[gn];
#pragma unroll
            for (int r = 0; r < 4; r++) {
                int gm = m0 + mf * 16 + q * 4 + r;
                if (gm < M) out[(long)gm * O_DIM + gn] = acc2[mf][nf][r] + bb;
            }
        }
    }
}

extern "C" void kernel_launch(void* const* d_in, const int* in_sizes, int n_in,
                              void* d_out, int out_size, void* d_ws, size_t ws_size,
                              hipStream_t stream) {
    const float* x  = (const float*)d_in[0];   // [N, C]
    const int*   ei = (const int*)d_in[1];     // [2, E]
    const float* w1 = (const float*)d_in[2];   // [2C, H]
    const float* b1 = (const float*)d_in[3];   // [H]
    const float* w2 = (const float*)d_in[4];   // [H, O]
    const float* b2 = (const float*)d_in[5];   // [O]
    float* out = (float*)d_out;                // [N, O]

    const int N = in_sizes[0] / C_IN;
    const int E = in_sizes[1] / 2;

    // ws layout: h0b [N][256] bf16 | w1t [512][256] bf16 | w2t [128][512] bf16
    //            | cnt_p [N*PAD] int | bucket [N*CAP] ushort
    unsigned short* h0b = (unsigned short*)d_ws;
    unsigned short* w1t = h0b + (size_t)N * (2 * C_IN);
    unsigned short* w2t = w1t + (size_t)H_DIM * (2 * C_IN);
    int* cnt_p = (int*)(w2t + (size_t)O_DIM * H_DIM);
    unsigned short* bucket = (unsigned short*)(cnt_p + (size_t)N * PAD);

    hipMemsetAsync(cnt_p, 0, (size_t)N * PAD * sizeof(int), stream);
    prep_fill<<<1024, 256, 0, stream>>>(w1, w1t, w2, w2t, x, h0b, ei, cnt_p, bucket, N, E);
    gather_kernel<<<(N + 3) / 4, 256, 0, stream>>>(bucket, cnt_p, h0b, N);
    fused_mlp<<<(N + BM - 1) / BM, 256, 0, stream>>>(h0b, w1t, b1, w2t, b2, out, N);
}